// Round 1
// baseline (258.750 us; speedup 1.0000x reference)
//
#include <hip/hip_runtime.h>
#include <cstdint>

// ---------------- Kernel 0: pack weight sign bits into ws ----------------
// pw layout (uint32):
//   [0..31]    wb1[c]        : 9-bit mask, bit (kh*3+kw) = (w1[c][0][kh][kw] > 0)
//   [32..607]  W2s[oc][tap]  : 32-bit mask, bit ic = (w2[oc][ic][kh][kw] > 0)
//   [608..895] W3s[oc][tap][2]: lo = ic 0..31, hi = ic 32..63
__global__ void pack_weights(const float* __restrict__ w1,
                             const float* __restrict__ w2,
                             const float* __restrict__ w3,
                             uint32_t* __restrict__ pw) {
    int t = threadIdx.x;
    if (t < 32) {
        uint32_t b = 0;
        for (int k = 0; k < 9; ++k) b |= (w1[t * 9 + k] > 0.f ? 1u : 0u) << k;
        pw[t] = b;
    }
    for (int idx = t; idx < 576; idx += blockDim.x) {
        int oc = idx / 9, tap = idx % 9;
        int kh = tap / 3, kw = tap % 3;
        uint32_t b = 0;
        for (int ic = 0; ic < 32; ++ic)
            b |= (w2[((oc * 32 + ic) * 3 + kh) * 3 + kw] > 0.f ? 1u : 0u) << ic;
        pw[32 + idx] = b;
    }
    for (int idx = t; idx < 144; idx += blockDim.x) {
        int oc = idx / 9, tap = idx % 9;
        int kh = tap / 3, kw = tap % 3;
        uint32_t lo = 0, hi = 0;
        for (int ic = 0; ic < 32; ++ic) {
            lo |= (w3[((oc * 64 + ic) * 3 + kh) * 3 + kw] > 0.f ? 1u : 0u) << ic;
            hi |= (w3[((oc * 64 + ic + 32) * 3 + kh) * 3 + kw] > 0.f ? 1u : 0u) << ic;
        }
        pw[608 + idx * 2] = lo;
        pw[608 + idx * 2 + 1] = hi;
    }
}

// ---------------- Kernel A: fused binary conv stack, one image per block ----
__global__ __launch_bounds__(256) void conv_stack(
    const float* __restrict__ x,
    const float* __restrict__ b1,
    const float* __restrict__ b2,
    const float* __restrict__ b3,
    const uint32_t* __restrict__ pw,
    float* __restrict__ h3g) {
    __shared__ uint32_t s_wb1[32];
    __shared__ uint32_t s_W2[576];
    __shared__ uint32_t s_W3[288];
    __shared__ float s_b1[32], s_b2[64], s_b3[16];
    __shared__ uint32_t s_xrow[28];
    __shared__ uint32_t s_H1[196];   // [14][14], bit c = sign of h1 channel c
    __shared__ uint32_t s_H2[98];    // [49][2], 64 channels

    const int t = threadIdx.x;
    const int img = blockIdx.x;

    if (t < 32) { s_wb1[t] = pw[t]; s_b1[t] = b1[t]; }
    if (t >= 32 && t < 96) s_b2[t - 32] = b2[t - 32];
    if (t >= 96 && t < 112) s_b3[t - 96] = b3[t - 96];
    for (int i = t; i < 576; i += 256) s_W2[i] = pw[32 + i];
    for (int i = t; i < 288; i += 256) s_W3[i] = pw[608 + i];
    if (t < 98) s_H2[t] = 0;
    if (t >= 128 && t < 156) {
        int r = t - 128;
        const float* xr = x + img * 784 + r * 28;
        uint32_t b = 0;
        for (int j = 0; j < 28; ++j) b |= (xr[j] > 0.f ? 1u : 0u) << j;
        s_xrow[r] = b;
    }
    __syncthreads();

    // ---- conv1 (1->32ch, 3x3 same) + maxpool2 + relu + binarize ----
    if (t < 196) {
        int pi = t / 14, pj = t % 14;
        uint32_t sarr[4], marr[4];
        int pcm[4];
#pragma unroll
        for (int p = 0; p < 4; ++p) {
            int i = 2 * pi + (p >> 1), j = 2 * pj + (p & 1);
            uint32_t sb = 0, mb = 0;
            int bit = 0;
#pragma unroll
            for (int di = -1; di <= 1; ++di) {
                int y = i + di;
                bool rv = (y >= 0 && y < 28);
                uint32_t row = rv ? s_xrow[y] : 0u;
#pragma unroll
                for (int dj = -1; dj <= 1; ++dj) {
                    int xx = j + dj;
                    bool v = rv && xx >= 0 && xx < 28;
                    if (v) {
                        mb |= 1u << bit;
                        sb |= ((row >> xx) & 1u) << bit;
                    }
                    ++bit;
                }
            }
            sarr[p] = sb; marr[p] = mb; pcm[p] = __popc(mb);
        }
        uint32_t word = 0;
#pragma unroll
        for (int c = 0; c < 32; ++c) {
            uint32_t w = s_wb1[c];
            int best = -100;
#pragma unroll
            for (int p = 0; p < 4; ++p) {
                int v = pcm[p] - 2 * __popc((sarr[p] ^ w) & marr[p]);
                best = v > best ? v : best;
            }
            word |= ((float)best + s_b1[c] > 0.f ? 1u : 0u) << c;
        }
        s_H1[t] = word;
    }
    __syncthreads();

    // ---- conv2 (32->64ch) + maxpool2 + relu + binarize ----
    // task = (quad of 4 out-channels) x (49 pooled positions)
    for (int task = t; task < 784; task += 256) {
        int quad = task / 49, pos = task % 49;
        int pi = pos / 7, pj = pos % 7;
        uint32_t cell[16];
        uint32_t vm = 0;
#pragma unroll
        for (int r = 0; r < 4; ++r) {
            int y = 2 * pi - 1 + r;
#pragma unroll
            for (int c = 0; c < 4; ++c) {
                int xx = 2 * pj - 1 + c;
                bool v = (y >= 0 && y < 14 && xx >= 0 && xx < 14);
                cell[r * 4 + c] = v ? s_H1[y * 14 + xx] : 0u;
                vm |= (v ? 1u : 0u) << (r * 4 + c);
            }
        }
        uint32_t nib = 0;
#pragma unroll
        for (int o = 0; o < 4; ++o) {
            int oc = quad * 4 + o;
            const uint32_t* wrow = &s_W2[oc * 9];
            int best = -10000;
#pragma unroll
            for (int p = 0; p < 4; ++p) {
                int a = p >> 1, b = p & 1;
                int acc = 0;
#pragma unroll
                for (int tap = 0; tap < 9; ++tap) {
                    int ci = (a + tap / 3) * 4 + (b + tap % 3);
                    int contrib = 32 - 2 * __popc(cell[ci] ^ wrow[tap]);
                    acc += ((vm >> ci) & 1u) ? contrib : 0;
                }
                best = acc > best ? acc : best;
            }
            nib |= ((float)best + s_b2[oc] > 0.f ? 1u : 0u) << (oc & 31);
        }
        atomicOr((unsigned int*)&s_H2[pos * 2 + (quad >> 3)], (unsigned int)nib);
    }
    __syncthreads();

    // ---- conv3 (64->16ch, no pool) + bias + relu -> fp32 h3 ----
    for (int task = t; task < 784; task += 256) {
        int oc = task / 49, pos = task % 49;
        int pi = pos / 7, pj = pos % 7;
        const uint32_t* wr = &s_W3[oc * 18];
        int acc = 0;
#pragma unroll
        for (int tap = 0; tap < 9; ++tap) {
            int y = pi + tap / 3 - 1, xx = pj + tap % 3 - 1;
            if (y >= 0 && y < 7 && xx >= 0 && xx < 7) {
                uint32_t lo = s_H2[(y * 7 + xx) * 2];
                uint32_t hi = s_H2[(y * 7 + xx) * 2 + 1];
                acc += 64 - 2 * (__popc(lo ^ wr[tap * 2]) + __popc(hi ^ wr[tap * 2 + 1]));
            }
        }
        float h = (float)acc + s_b3[oc];
        h3g[img * 784 + oc * 49 + pos] = h > 0.f ? h : 0.f;
    }
}

// ---------------- Kernel B: fused FC1+FC2+FC3, 16 images per block ----------
__global__ __launch_bounds__(256) void fc_stack(
    const float* __restrict__ h3g,
    const float* __restrict__ fc1_w, const float* __restrict__ fc1_b,
    const float* __restrict__ fc2_w, const float* __restrict__ fc2_b,
    const float* __restrict__ fc3_w, const float* __restrict__ fc3_b,
    float* __restrict__ out) {
    __shared__ __align__(16) float smem[784 * 20];  // 62.7 KB, regions reused
    float* s_h = smem;                    // [784][20] (16 imgs + pad)
    float* s_o1 = smem;                   // after FC1: [256][20]
    float* s_part = smem + 256 * 20;      // [256][16]
    float* s_o2 = smem + 256 * 20 + 256 * 16;  // [128][20]

    const int t = threadIdx.x;
    const int ib = blockIdx.x * 16;

    // stage h3 for 16 images, [k][img] layout for vectorized broadcast reads
    for (int idx = t; idx < 16 * 784; idx += 256) {
        int i = idx / 784, k = idx % 784;
        s_h[k * 20 + i] = h3g[(ib + i) * 784 + k];
    }
    __syncthreads();

    // ---- FC1: 784 -> 256, thread t = neuron t, 16 images each ----
    float acc[16];
#pragma unroll
    for (int i = 0; i < 16; ++i) acc[i] = 0.f;
    {
        const float4* wrow = (const float4*)(fc1_w + t * 784);
        for (int k4 = 0; k4 < 196; ++k4) {
            float4 w = wrow[k4];
            float wv[4] = {w.x, w.y, w.z, w.w};
#pragma unroll
            for (int j = 0; j < 4; ++j) {
                const float4* h4 = (const float4*)(s_h + (k4 * 4 + j) * 20);
#pragma unroll
                for (int q = 0; q < 4; ++q) {
                    float4 hv = h4[q];
                    acc[q * 4 + 0] += wv[j] * hv.x;
                    acc[q * 4 + 1] += wv[j] * hv.y;
                    acc[q * 4 + 2] += wv[j] * hv.z;
                    acc[q * 4 + 3] += wv[j] * hv.w;
                }
            }
        }
    }
    float bn1 = fc1_b[t];
    __syncthreads();   // all reads of s_h done; safe to overwrite region
#pragma unroll
    for (int i = 0; i < 16; ++i) {
        float v = acc[i] + bn1;
        s_o1[t * 20 + i] = v > 0.f ? v : 0.f;
    }
    __syncthreads();

    // ---- FC2: 256 -> 128, thread = (neuron n, k-half) ----
    {
        int n = t & 127, half = t >> 7;
#pragma unroll
        for (int i = 0; i < 16; ++i) acc[i] = 0.f;
        const float4* wrow = (const float4*)(fc2_w + n * 256 + half * 128);
        for (int k4 = 0; k4 < 32; ++k4) {
            float4 w = wrow[k4];
            float wv[4] = {w.x, w.y, w.z, w.w};
#pragma unroll
            for (int j = 0; j < 4; ++j) {
                const float4* h4 = (const float4*)(s_o1 + (half * 128 + k4 * 4 + j) * 20);
#pragma unroll
                for (int q = 0; q < 4; ++q) {
                    float4 hv = h4[q];
                    acc[q * 4 + 0] += wv[j] * hv.x;
                    acc[q * 4 + 1] += wv[j] * hv.y;
                    acc[q * 4 + 2] += wv[j] * hv.z;
                    acc[q * 4 + 3] += wv[j] * hv.w;
                }
            }
        }
#pragma unroll
        for (int i = 0; i < 16; ++i) s_part[(half * 128 + n) * 16 + i] = acc[i];
    }
    __syncthreads();

    // combine halves + bias + relu -> s_o2 [128][20]
    for (int idx = t; idx < 128 * 16; idx += 256) {
        int n = idx / 16, i = idx % 16;
        float v = s_part[n * 16 + i] + s_part[(128 + n) * 16 + i] + fc2_b[n];
        s_o2[n * 20 + i] = v > 0.f ? v : 0.f;
    }
    __syncthreads();

    // ---- FC3: 128 -> 10 ----
    if (t < 160) {
        int i = t / 10, n = t % 10;
        float a3 = fc3_b[n];
        const float* wr = fc3_w + n * 128;
        for (int k = 0; k < 128; ++k) a3 += wr[k] * s_o2[k * 20 + i];
        out[(ib + i) * 10 + n] = a3;
    }
}

extern "C" void kernel_launch(void* const* d_in, const int* in_sizes, int n_in,
                              void* d_out, int out_size, void* d_ws, size_t ws_size,
                              hipStream_t stream) {
    const float* x     = (const float*)d_in[0];
    const float* w1    = (const float*)d_in[1];
    const float* b1    = (const float*)d_in[2];
    const float* w2    = (const float*)d_in[3];
    const float* b2    = (const float*)d_in[4];
    const float* w3    = (const float*)d_in[5];
    const float* b3    = (const float*)d_in[6];
    const float* fc1_w = (const float*)d_in[7];
    const float* fc1_b = (const float*)d_in[8];
    const float* fc2_w = (const float*)d_in[9];
    const float* fc2_b = (const float*)d_in[10];
    const float* fc3_w = (const float*)d_in[11];
    const float* fc3_b = (const float*)d_in[12];
    float* out = (float*)d_out;

    const int B = in_sizes[0] / 784;  // 4096

    uint32_t* pw = (uint32_t*)d_ws;
    float* h3g = (float*)((char*)d_ws + 4096);

    hipLaunchKernelGGL(pack_weights, dim3(1), dim3(256), 0, stream, w1, w2, w3, pw);
    hipLaunchKernelGGL(conv_stack, dim3(B), dim3(256), 0, stream,
                       x, b1, b2, b3, pw, h3g);
    hipLaunchKernelGGL(fc_stack, dim3(B / 16), dim3(256), 0, stream,
                       h3g, fc1_w, fc1_b, fc2_w, fc2_b, fc3_w, fc3_b, out);
}

// Round 2
// 220.111 us; speedup vs baseline: 1.1755x; 1.1755x over previous
//
#include <hip/hip_runtime.h>
#include <cstdint>

// ---------------- ws layout (bytes) ----------------
// pw      @ 0        : 896 uint32 packed weight bits
// fc1_wT  @ 4096     : [800][256] f32 (zero-padded k>=784)   819200 B
// fc2_wT  @ 823296   : [256][128] f32                        131072 B
// h3T     @ 954368   : [800][4096] f32 (rows>=784 unused)  13107200 B
// h1T     @ 14061568 : [256][4096] f32                      4194304 B
// h2T     @ 18255872 : [128][4096] f32                      2097152 B
#define OFF_PW    0
#define OFF_W1T   4096
#define OFF_W2T   823296
#define OFF_H3T   954368
#define OFF_H1T   14061568
#define OFF_H2T   18255872

// ---------------- prep: pack conv weight bits + transpose FC weights --------
__global__ __launch_bounds__(256) void prep(
    const float* __restrict__ w1, const float* __restrict__ w2,
    const float* __restrict__ w3,
    const float* __restrict__ fc1_w, const float* __restrict__ fc2_w,
    uint32_t* __restrict__ pw, float* __restrict__ w1T, float* __restrict__ w2T) {
    int t = threadIdx.x;
    if (blockIdx.x == 0) {
        if (t < 32) {
            uint32_t b = 0;
            for (int k = 0; k < 9; ++k) b |= (w1[t * 9 + k] > 0.f ? 1u : 0u) << k;
            pw[t] = b;
        }
        for (int idx = t; idx < 576; idx += 256) {
            int oc = idx / 9, tap = idx % 9;
            int kh = tap / 3, kw = tap % 3;
            uint32_t b = 0;
            for (int ic = 0; ic < 32; ++ic)
                b |= (w2[((oc * 32 + ic) * 3 + kh) * 3 + kw] > 0.f ? 1u : 0u) << ic;
            pw[32 + idx] = b;
        }
        for (int idx = t; idx < 144; idx += 256) {
            int oc = idx / 9, tap = idx % 9;
            int kh = tap / 3, kw = tap % 3;
            uint32_t lo = 0, hi = 0;
            for (int ic = 0; ic < 32; ++ic) {
                lo |= (w3[((oc * 64 + ic) * 3 + kh) * 3 + kw] > 0.f ? 1u : 0u) << ic;
                hi |= (w3[((oc * 64 + ic + 32) * 3 + kh) * 3 + kw] > 0.f ? 1u : 0u) << ic;
            }
            pw[608 + idx * 2] = lo;
            pw[608 + idx * 2 + 1] = hi;
        }
    } else {
        int e = (blockIdx.x - 1) * 256 + t;
        if (e < 204800) {                 // fc1_wT [800][256]
            int k = e >> 8, n = e & 255;
            w1T[e] = (k < 784) ? fc1_w[n * 784 + k] : 0.f;
        } else {                          // fc2_wT [256][128]
            int e2 = e - 204800;          // < 32768
            int k = e2 >> 7, n = e2 & 127;
            w2T[e2] = fc2_w[n * 256 + k];
        }
    }
}

// ---------------- conv stack: one image per block, xnor-popcount ------------
__global__ __launch_bounds__(256) void conv_stack(
    const float* __restrict__ x,
    const float* __restrict__ b1, const float* __restrict__ b2,
    const float* __restrict__ b3,
    const uint32_t* __restrict__ pw,
    float* __restrict__ h3T) {            // [800][4096]
    __shared__ uint32_t s_wb1[32];
    __shared__ uint32_t s_W2[576];
    __shared__ uint32_t s_W3[288];
    __shared__ float s_b1[32], s_b2[64], s_b3[16];
    __shared__ uint32_t s_xrow[28];
    __shared__ uint32_t s_H1[256];   // padded 16x16, zero border
    __shared__ uint32_t s_H2[162];   // padded 9x9 x 2 words, zero border

    const int t = threadIdx.x;
    const int img = blockIdx.x;

    s_H1[t] = 0;
    if (t < 162) s_H2[t] = 0;
    if (t < 32) { s_wb1[t] = pw[t]; s_b1[t] = b1[t]; }
    if (t >= 32 && t < 96) s_b2[t - 32] = b2[t - 32];
    if (t >= 96 && t < 112) s_b3[t - 96] = b3[t - 96];
    for (int i = t; i < 576; i += 256) s_W2[i] = pw[32 + i];
    for (int i = t; i < 288; i += 256) s_W3[i] = pw[608 + i];
    if (t >= 192 && t < 220) {
        int r = t - 192;
        const float* xr = x + img * 784 + r * 28;
        uint32_t b = 0;
        for (int j = 0; j < 28; ++j) b |= (xr[j] > 0.f ? 1u : 0u) << j;
        s_xrow[r] = b;
    }
    __syncthreads();

    // ---- conv1 (1->32) + pool + relu + binarize -> padded s_H1 ----
    if (t < 196) {
        int pi = t / 14, pj = t % 14;
        uint32_t sarr[4], marr[4];
        int pcm[4];
#pragma unroll
        for (int p = 0; p < 4; ++p) {
            int i = 2 * pi + (p >> 1), j = 2 * pj + (p & 1);
            uint32_t sb = 0, mb = 0;
            int bit = 0;
#pragma unroll
            for (int di = -1; di <= 1; ++di) {
                int y = i + di;
                bool rv = (unsigned)y < 28u;
                uint32_t row = rv ? s_xrow[rv ? y : 0] : 0u;
#pragma unroll
                for (int dj = -1; dj <= 1; ++dj) {
                    int xx = j + dj;
                    bool v = rv && (unsigned)xx < 28u;
                    if (v) {
                        mb |= 1u << bit;
                        sb |= ((row >> xx) & 1u) << bit;
                    }
                    ++bit;
                }
            }
            sarr[p] = sb; marr[p] = mb; pcm[p] = __popc(mb);
        }
        uint32_t word = 0;
#pragma unroll
        for (int c = 0; c < 32; ++c) {
            uint32_t w = s_wb1[c];
            int best = -1000;
#pragma unroll
            for (int p = 0; p < 4; ++p) {
                int v = pcm[p] - 2 * __popc((sarr[p] ^ w) & marr[p]);
                best = v > best ? v : best;
            }
            word |= ((float)best + s_b1[c] > 0.f ? 1u : 0u) << c;
        }
        s_H1[(pi + 1) * 16 + (pj + 1)] = word;
    }
    __syncthreads();

    // ---- conv2 (32->64) + pool + relu + binarize ----
    // interior pooled positions (pi,pj in 1..5): all taps valid, no masking
    for (int task = t; task < 400; task += 256) {
        int q = task / 25, ip = task - q * 25;
        int pi = ip / 5 + 1, pj = ip % 5 + 1;
        uint32_t cell[16];
#pragma unroll
        for (int r = 0; r < 4; ++r)
#pragma unroll
            for (int c = 0; c < 4; ++c)
                cell[r * 4 + c] = s_H1[(2 * pi + r) * 16 + (2 * pj + c)];
        uint32_t nib = 0;
#pragma unroll
        for (int o = 0; o < 4; ++o) {
            int oc = q * 4 + o;
            const uint32_t* wrow = &s_W2[oc * 9];
            int best = -100000;
#pragma unroll
            for (int a = 0; a < 2; ++a)
#pragma unroll
                for (int b = 0; b < 2; ++b) {
                    int S = 0;
#pragma unroll
                    for (int kh = 0; kh < 3; ++kh)
#pragma unroll
                        for (int kw = 0; kw < 3; ++kw)
                            S += __popc(cell[(a + kh) * 4 + (b + kw)] ^ wrow[kh * 3 + kw]);
                    int v = 288 - 2 * S;
                    best = v > best ? v : best;
                }
            nib |= ((float)best + s_b2[oc] > 0.f ? 1u : 0u) << (oc & 31);
        }
        atomicOr((unsigned int*)&s_H2[((pi + 1) * 9 + (pj + 1)) * 2 + (q >> 3)],
                 (unsigned int)nib);
    }
    // border pooled positions: masked taps via V words
    for (int task = t; task < 384; task += 256) {
        int q = task / 24, bp = task - q * 24;
        int pi, pj;
        if (bp < 7)       { pi = 0; pj = bp; }
        else if (bp < 14) { pi = 6; pj = bp - 7; }
        else if (bp < 19) { pi = bp - 13; pj = 0; }
        else              { pi = bp - 18; pj = 6; }
        uint32_t vr[4], vc[4];
#pragma unroll
        for (int r = 0; r < 4; ++r) {
            vr[r] = ((unsigned)(2 * pi - 1 + r) < 14u) ? 0xFFFFFFFFu : 0u;
            vc[r] = ((unsigned)(2 * pj - 1 + r) < 14u) ? 0xFFFFFFFFu : 0u;
        }
        uint32_t cell[16], V[16];
#pragma unroll
        for (int r = 0; r < 4; ++r)
#pragma unroll
            for (int c = 0; c < 4; ++c) {
                cell[r * 4 + c] = s_H1[(2 * pi + r) * 16 + (2 * pj + c)];
                V[r * 4 + c] = vr[r] & vc[c];
            }
        int nvp[4];
#pragma unroll
        for (int a = 0; a < 2; ++a)
#pragma unroll
            for (int b = 0; b < 2; ++b) {
                int i = 2 * pi + a, j = 2 * pj + b;
                int vy = 3 - (i == 0) - (i == 13);
                int vx = 3 - (j == 0) - (j == 13);
                nvp[a * 2 + b] = 32 * vy * vx;
            }
        uint32_t nib = 0;
#pragma unroll
        for (int o = 0; o < 4; ++o) {
            int oc = q * 4 + o;
            const uint32_t* wrow = &s_W2[oc * 9];
            int best = -100000;
#pragma unroll
            for (int a = 0; a < 2; ++a)
#pragma unroll
                for (int b = 0; b < 2; ++b) {
                    int S = 0;
#pragma unroll
                    for (int kh = 0; kh < 3; ++kh)
#pragma unroll
                        for (int kw = 0; kw < 3; ++kw) {
                            int ci = (a + kh) * 4 + (b + kw);
                            S += __popc((cell[ci] ^ wrow[kh * 3 + kw]) & V[ci]);
                        }
                    int v = nvp[a * 2 + b] - 2 * S;
                    best = v > best ? v : best;
                }
            nib |= ((float)best + s_b2[oc] > 0.f ? 1u : 0u) << (oc & 31);
        }
        atomicOr((unsigned int*)&s_H2[((pi + 1) * 9 + (pj + 1)) * 2 + (q >> 3)],
                 (unsigned int)nib);
    }
    __syncthreads();

    // ---- conv3 (64->16) + bias + relu -> h3T[k][img] ----
    for (int task = t; task < 784; task += 256) {
        int oc = task / 49, pos = task - oc * 49;
        int pi = pos / 7, pj = pos % 7;
        uint32_t vr[3], vc[3];
#pragma unroll
        for (int d = 0; d < 3; ++d) {
            vr[d] = ((unsigned)(pi - 1 + d) < 7u) ? 0xFFFFFFFFu : 0u;
            vc[d] = ((unsigned)(pj - 1 + d) < 7u) ? 0xFFFFFFFFu : 0u;
        }
        int vy = 3 - (pi == 0) - (pi == 6);
        int vx = 3 - (pj == 0) - (pj == 6);
        int Nv = 64 * vy * vx;
        const uint32_t* wr = &s_W3[oc * 18];
        int S = 0;
#pragma unroll
        for (int kh = 0; kh < 3; ++kh)
#pragma unroll
            for (int kw = 0; kw < 3; ++kw) {
                uint32_t V = vr[kh] & vc[kw];
                int idx = ((pi + kh) * 9 + (pj + kw)) * 2;
                S += __popc((s_H2[idx] ^ wr[(kh * 3 + kw) * 2]) & V);
                S += __popc((s_H2[idx + 1] ^ wr[(kh * 3 + kw) * 2 + 1]) & V);
            }
        float h = (float)(Nv - 2 * S) + s_b3[oc];
        h3T[task * 4096 + img] = h > 0.f ? h : 0.f;
    }
}

// ---------------- FC1: [4096x800] x [800x256] -> relu -> h1T ----------------
__global__ __launch_bounds__(256) void fc1_gemm(
    const float* __restrict__ aT,    // h3T [800][4096]
    const float* __restrict__ bT,    // fc1_wT [800][256]
    const float* __restrict__ bias,
    float* __restrict__ oT) {        // h1T [256][4096]
    const int KC = 80, LD = 68;
    __shared__ float As[KC * LD];
    __shared__ float Bs[KC * LD];
    const int t = threadIdx.x;
    const int tx = t & 15, ty = t >> 4;
    const int img0 = blockIdx.x * 64;
    const int n0 = blockIdx.y * 64;
    float acc[4][4] = {{0.f}};

    for (int kc = 0; kc < 800; kc += KC) {
#pragma unroll
        for (int s = 0; s < 5; ++s) {
            int v = t + s * 256;
            int kk = v >> 4, i4 = (v & 15) * 4;
            *(float4*)&As[kk * LD + i4] =
                *(const float4*)&aT[(kc + kk) * 4096 + img0 + i4];
            *(float4*)&Bs[kk * LD + i4] =
                *(const float4*)&bT[(kc + kk) * 256 + n0 + i4];
        }
        __syncthreads();
#pragma unroll 4
        for (int kk = 0; kk < KC; ++kk) {
            float4 a = *(const float4*)&As[kk * LD + ty * 4];
            float4 b = *(const float4*)&Bs[kk * LD + tx * 4];
            acc[0][0] += a.x * b.x; acc[0][1] += a.x * b.y;
            acc[0][2] += a.x * b.z; acc[0][3] += a.x * b.w;
            acc[1][0] += a.y * b.x; acc[1][1] += a.y * b.y;
            acc[1][2] += a.y * b.z; acc[1][3] += a.y * b.w;
            acc[2][0] += a.z * b.x; acc[2][1] += a.z * b.y;
            acc[2][2] += a.z * b.z; acc[2][3] += a.z * b.w;
            acc[3][0] += a.w * b.x; acc[3][1] += a.w * b.y;
            acc[3][2] += a.w * b.z; acc[3][3] += a.w * b.w;
        }
        __syncthreads();
    }
    float4 bb = *(const float4*)&bias[n0 + tx * 4];
    float bv[4] = {bb.x, bb.y, bb.z, bb.w};
#pragma unroll
    for (int jj = 0; jj < 4; ++jj) {
        float4 ov;
        ov.x = acc[0][jj] + bv[jj]; ov.x = ov.x > 0.f ? ov.x : 0.f;
        ov.y = acc[1][jj] + bv[jj]; ov.y = ov.y > 0.f ? ov.y : 0.f;
        ov.z = acc[2][jj] + bv[jj]; ov.z = ov.z > 0.f ? ov.z : 0.f;
        ov.w = acc[3][jj] + bv[jj]; ov.w = ov.w > 0.f ? ov.w : 0.f;
        *(float4*)&oT[(n0 + tx * 4 + jj) * 4096 + img0 + ty * 4] = ov;
    }
}

// ---------------- FC2: [4096x256] x [256x128] -> relu -> h2T ----------------
__global__ __launch_bounds__(256) void fc2_gemm(
    const float* __restrict__ aT,    // h1T [256][4096]
    const float* __restrict__ bT,    // fc2_wT [256][128]
    const float* __restrict__ bias,
    float* __restrict__ oT) {        // h2T [128][4096]
    const int KC = 64, LDA = 68, LDB = 36;
    __shared__ float As[KC * LDA];
    __shared__ float Bs[KC * LDB];
    const int t = threadIdx.x;
    const int tx = t & 15, ty = t >> 4;
    const int img0 = blockIdx.x * 64;
    const int n0 = blockIdx.y * 32;
    float acc[4][2] = {{0.f}};

    for (int kc = 0; kc < 256; kc += KC) {
#pragma unroll
        for (int s = 0; s < 4; ++s) {
            int v = t + s * 256;
            int kk = v >> 4, i4 = (v & 15) * 4;
            *(float4*)&As[kk * LDA + i4] =
                *(const float4*)&aT[(kc + kk) * 4096 + img0 + i4];
        }
#pragma unroll
        for (int s = 0; s < 2; ++s) {
            int v = t + s * 256;
            int kk = v >> 3, n4 = (v & 7) * 4;
            *(float4*)&Bs[kk * LDB + n4] =
                *(const float4*)&bT[(kc + kk) * 128 + n0 + n4];
        }
        __syncthreads();
#pragma unroll 4
        for (int kk = 0; kk < KC; ++kk) {
            float4 a = *(const float4*)&As[kk * LDA + ty * 4];
            float2 b = *(const float2*)&Bs[kk * LDB + tx * 2];
            acc[0][0] += a.x * b.x; acc[0][1] += a.x * b.y;
            acc[1][0] += a.y * b.x; acc[1][1] += a.y * b.y;
            acc[2][0] += a.z * b.x; acc[2][1] += a.z * b.y;
            acc[3][0] += a.w * b.x; acc[3][1] += a.w * b.y;
        }
        __syncthreads();
    }
#pragma unroll
    for (int j = 0; j < 2; ++j) {
        int n = n0 + tx * 2 + j;
        float bj = bias[n];
        float4 ov;
        ov.x = acc[0][j] + bj; ov.x = ov.x > 0.f ? ov.x : 0.f;
        ov.y = acc[1][j] + bj; ov.y = ov.y > 0.f ? ov.y : 0.f;
        ov.z = acc[2][j] + bj; ov.z = ov.z > 0.f ? ov.z : 0.f;
        ov.w = acc[3][j] + bj; ov.w = ov.w > 0.f ? ov.w : 0.f;
        *(float4*)&oT[n * 4096 + img0 + ty * 4] = ov;
    }
}

// ---------------- FC3: [4096x128] x [128x10] -> out -------------------------
__global__ __launch_bounds__(256) void fc3_gemm(
    const float* __restrict__ aT,    // h2T [128][4096]
    const float* __restrict__ w,     // fc3_w [10][128]
    const float* __restrict__ bias,
    float* __restrict__ out) {       // [4096][10]
    int id = blockIdx.x * 256 + threadIdx.x;   // 40960
    int n = id >> 12, img = id & 4095;
    const float* wr = w + n * 128;
    float a0 = 0.f, a1 = 0.f, a2 = 0.f, a3 = 0.f;
#pragma unroll 8
    for (int k = 0; k < 128; k += 4) {
        a0 += aT[(k + 0) * 4096 + img] * wr[k + 0];
        a1 += aT[(k + 1) * 4096 + img] * wr[k + 1];
        a2 += aT[(k + 2) * 4096 + img] * wr[k + 2];
        a3 += aT[(k + 3) * 4096 + img] * wr[k + 3];
    }
    out[img * 10 + n] = (a0 + a1) + (a2 + a3) + bias[n];
}

extern "C" void kernel_launch(void* const* d_in, const int* in_sizes, int n_in,
                              void* d_out, int out_size, void* d_ws, size_t ws_size,
                              hipStream_t stream) {
    const float* x     = (const float*)d_in[0];
    const float* w1    = (const float*)d_in[1];
    const float* b1    = (const float*)d_in[2];
    const float* w2    = (const float*)d_in[3];
    const float* b2    = (const float*)d_in[4];
    const float* w3    = (const float*)d_in[5];
    const float* b3    = (const float*)d_in[6];
    const float* fc1_w = (const float*)d_in[7];
    const float* fc1_b = (const float*)d_in[8];
    const float* fc2_w = (const float*)d_in[9];
    const float* fc2_b = (const float*)d_in[10];
    const float* fc3_w = (const float*)d_in[11];
    const float* fc3_b = (const float*)d_in[12];
    float* out = (float*)d_out;

    const int B = in_sizes[0] / 784;  // 4096
    char* ws = (char*)d_ws;
    uint32_t* pw = (uint32_t*)(ws + OFF_PW);
    float* w1T = (float*)(ws + OFF_W1T);
    float* w2T = (float*)(ws + OFF_W2T);
    float* h3T = (float*)(ws + OFF_H3T);
    float* h1T = (float*)(ws + OFF_H1T);
    float* h2T = (float*)(ws + OFF_H2T);

    hipLaunchKernelGGL(prep, dim3(929), dim3(256), 0, stream,
                       w1, w2, w3, fc1_w, fc2_w, pw, w1T, w2T);
    hipLaunchKernelGGL(conv_stack, dim3(B), dim3(256), 0, stream,
                       x, b1, b2, b3, pw, h3T);
    hipLaunchKernelGGL(fc1_gemm, dim3(B / 64, 4), dim3(256), 0, stream,
                       h3T, w1T, fc1_b, h1T);
    hipLaunchKernelGGL(fc2_gemm, dim3(B / 64, 4), dim3(256), 0, stream,
                       h1T, w2T, fc2_b, h2T);
    hipLaunchKernelGGL(fc3_gemm, dim3(B * 10 / 256), dim3(256), 0, stream,
                       h2T, fc3_w, fc3_b, out);
}